// Round 1
// baseline (3354.991 us; speedup 1.0000x reference)
//
#include <hip/hip_runtime.h>

#define HDIM 256
#define G3 768

typedef __attribute__((ext_vector_type(8))) unsigned short ushort8;

__device__ __forceinline__ float bf2f(unsigned short u) {
  union { unsigned int i; float f; } v; v.i = ((unsigned int)u) << 16; return v.f;
}

__device__ __forceinline__ unsigned short f2bf(float f) {
  union { float f; unsigned int i; } v; v.f = f;
  unsigned int x = v.i;
  return (unsigned short)((x + 0x7fffu + ((x >> 16) & 1u)) >> 16);
}

// pack one weight matrix [2][768][256] f32 -> [2][3][32][256][8] bf16
// dst layout flat index: (((dir*3+g)*32+c)*256+j)*8+e  == src[dir*768 + g*256 + j][c*8+e]
__global__ __launch_bounds__(256) void pack_w(
    const float* __restrict__ s0, const float* __restrict__ s1,
    const float* __restrict__ s2, const float* __restrict__ s3,
    const float* __restrict__ s4, const float* __restrict__ s5,
    unsigned short* __restrict__ dst) {
  const float* srcs[6] = {s0, s1, s2, s3, s4, s5};
  const int mat = blockIdx.y;
  const float* src = srcs[mat];
  unsigned short* d = dst + (size_t)mat * 393216;
  int i = blockIdx.x * blockDim.x + threadIdx.x;  // group id, 49152 per matrix
  if (i >= 49152) return;
  int j = i & 255;
  int c = (i >> 8) & 31;
  int rest = i >> 13;      // dir*3+g
  int g = rest % 3;
  int dir = rest / 3;
  const float* sp = src + ((size_t)(dir * 768 + g * 256 + j)) * 256 + c * 8;
  unsigned short* dp = d + (size_t)i * 8;
#pragma unroll
  for (int e = 0; e < 8; ++e) dp[e] = f2bf(sp[e]);
}

// One GEMM phase: acc[g][m] += sum_k src[m][k] * W[g][k-chunk][j] for the
// thread's column j.  W packed as [3][32][256][8] bf16 (per direction).
template <int CHUNK>
__device__ __forceinline__ void gemm_phase(
    const unsigned short* __restrict__ W, const float* __restrict__ src, int j,
    float (&racc)[CHUNK], float (&zacc)[CHUNK], float (&nacc)[CHUNK]) {
#pragma unroll 2
  for (int c = 0; c < 32; ++c) {
    const ushort8 wr = *(const ushort8*)(W + ((size_t)((0 * 32 + c) * 256 + j)) * 8);
    const ushort8 wz = *(const ushort8*)(W + ((size_t)((1 * 32 + c) * 256 + j)) * 8);
    const ushort8 wn = *(const ushort8*)(W + ((size_t)((2 * 32 + c) * 256 + j)) * 8);
    float wrF[8], wzF[8], wnF[8];
#pragma unroll
    for (int e = 0; e < 8; ++e) {
      wrF[e] = bf2f(wr[e]); wzF[e] = bf2f(wz[e]); wnF[e] = bf2f(wn[e]);
    }
#pragma unroll
    for (int m = 0; m < CHUNK; ++m) {
      const float* xr = src + m * HDIM + c * 8;
      float4 a = *(const float4*)(xr);
      float4 b = *(const float4*)(xr + 4);
      racc[m] = fmaf(a.x, wrF[0], fmaf(a.y, wrF[1], fmaf(a.z, wrF[2], fmaf(a.w, wrF[3], racc[m]))));
      racc[m] = fmaf(b.x, wrF[4], fmaf(b.y, wrF[5], fmaf(b.z, wrF[6], fmaf(b.w, wrF[7], racc[m]))));
      zacc[m] = fmaf(a.x, wzF[0], fmaf(a.y, wzF[1], fmaf(a.z, wzF[2], fmaf(a.w, wzF[3], zacc[m]))));
      zacc[m] = fmaf(b.x, wzF[4], fmaf(b.y, wzF[5], fmaf(b.z, wzF[6], fmaf(b.w, wzF[7], zacc[m]))));
      nacc[m] = fmaf(a.x, wnF[0], fmaf(a.y, wnF[1], fmaf(a.z, wnF[2], fmaf(a.w, wnF[3], nacc[m]))));
      nacc[m] = fmaf(b.x, wnF[4], fmaf(b.y, wnF[5], fmaf(b.z, wnF[6], fmaf(b.w, wnF[7], nacc[m]))));
    }
  }
}

// Persistent bidirectional GRU over T steps. Block handles CHUNK sequences,
// both directions. Thread j owns gate/hidden column j (gate update is
// columnwise elementwise -> no cross-thread reduction).
// Word level: xbase=emb, idx=token ids (row = idx[n*T+t]).
// Other levels: idx=nullptr, row = n*T+t into xbase.
template <int CHUNK>
__global__ __launch_bounds__(256) void gru_bi(
    const float* __restrict__ xbase, const int* __restrict__ idx,
    const unsigned short* __restrict__ Wih, const unsigned short* __restrict__ Whh,
    const float* __restrict__ bih, const float* __restrict__ bhh,
    float* __restrict__ out, int T) {
  __shared__ float sx[2][CHUNK][HDIM];
  __shared__ float sh[2][CHUNK][HDIM];
  const int tid = threadIdx.x;
  const int j = tid;  // 256 threads == H columns
  const int n0 = blockIdx.x * CHUNK;

  for (int v = tid; v < 2 * CHUNK * HDIM; v += 256) ((float*)sh)[v] = 0.f;

  float br[2], bz[2], bxn[2], bhn[2];
#pragma unroll
  for (int d = 0; d < 2; ++d) {
    br[d] = bih[d * G3 + j] + bhh[d * G3 + j];
    bz[d] = bih[d * G3 + 256 + j] + bhh[d * G3 + 256 + j];
    bxn[d] = bih[d * G3 + 512 + j];
    bhn[d] = bhh[d * G3 + 512 + j];
  }

  float hfr[CHUNK], hbr[CHUNK];

  for (int t = 0; t < T; ++t) {
    // stage x rows for both directions (fp32, coalesced float4)
    for (int v = tid; v < 2 * CHUNK * 64; v += 256) {
      int d = v / (CHUNK * 64);
      int rem = v - d * (CHUNK * 64);
      int m = rem >> 6;
      int q = rem & 63;
      int tt = d ? (T - 1 - t) : t;
      int n = n0 + m;
      int row = idx ? idx[n * T + tt] : (n * T + tt);
      const float4* src = (const float4*)(xbase + (size_t)row * HDIM);
      ((float4*)sx[d][m])[q] = src[q];
    }
    __syncthreads();  // x staged; h writes from prev step visible

#pragma unroll
    for (int d = 0; d < 2; ++d) {
      float racc[CHUNK], zacc[CHUNK], nx[CHUNK], nh[CHUNK];
#pragma unroll
      for (int m = 0; m < CHUNK; ++m) {
        racc[m] = br[d]; zacc[m] = bz[d]; nx[m] = bxn[d]; nh[m] = bhn[d];
      }
      const unsigned short* Wx = Wih + (size_t)d * 196608;
      const unsigned short* Wh = Whh + (size_t)d * 196608;
      const float* px = &sx[d][0][0];
      const float* ph = &sh[d][0][0];
      gemm_phase<CHUNK>(Wx, px, j, racc, zacc, nx);
      gemm_phase<CHUNK>(Wh, ph, j, racc, zacc, nh);
#pragma unroll
      for (int m = 0; m < CHUNK; ++m) {
        float r = 1.f / (1.f + __expf(-racc[m]));
        float z = 1.f / (1.f + __expf(-zacc[m]));
        float nv = nx[m] + r * nh[m];
        float e2 = __expf(-2.f * nv);
        float n = (1.f - e2) / (1.f + e2);
        float hprev = ph[m * HDIM + j];
        float hnew = (1.f - z) * n + z * hprev;
        if (d == 0) hfr[m] = hnew; else hbr[m] = hnew;
      }
    }
    __syncthreads();  // all gate reads of h done
#pragma unroll
    for (int m = 0; m < CHUNK; ++m) {
      sh[0][m][j] = hfr[m];
      sh[1][m][j] = hbr[m];
    }
  }

#pragma unroll
  for (int m = 0; m < CHUNK; ++m)
    out[(size_t)(n0 + m) * HDIM + j] = hfr[m] + hbr[m];
}

// FC heads: blocks 0..127 -> r_stars from rev rows, blocks 128..135 -> b_stars
// from biz rows. Linear(256->128) -> SELU -> Linear(128->1).
__global__ __launch_bounds__(128) void fc_head(
    const float* __restrict__ rev, const float* __restrict__ biz,
    const float* __restrict__ rW1, const float* __restrict__ rb1,
    const float* __restrict__ rW2, const float* __restrict__ rb2,
    const float* __restrict__ pW1, const float* __restrict__ pb1,
    const float* __restrict__ pW2, const float* __restrict__ pb2,
    float* __restrict__ out) {
  const int b = blockIdx.x;
  const int tid = threadIdx.x;
  const float *x, *W1, *b1, *W2, *b2;
  float* o;
  if (b < 128) {
    x = rev + (size_t)b * 256; W1 = rW1; b1 = rb1; W2 = rW2; b2 = rb2; o = out + 8 + b;
  } else {
    int bb = b - 128;
    x = biz + (size_t)bb * 256; W1 = pW1; b1 = pb1; W2 = pW2; b2 = pb2; o = out + bb;
  }
  float acc = 0.f;
  const float4* x4 = (const float4*)x;
  const float4* w4 = (const float4*)(W1 + (size_t)tid * 256);
#pragma unroll 4
  for (int k = 0; k < 64; ++k) {
    float4 a = x4[k], w = w4[k];
    acc = fmaf(a.x, w.x, fmaf(a.y, w.y, fmaf(a.z, w.z, fmaf(a.w, w.w, acc))));
  }
  acc += b1[tid];
  const float LAM = 1.0507009873554805f, ALPHA = 1.6732632423543772f;
  float h = acc > 0.f ? LAM * acc : LAM * ALPHA * (__expf(acc) - 1.f);
  __shared__ float p[128];
  p[tid] = h * W2[tid];
  __syncthreads();
  if (tid == 0) {
    float s = b2[0];
#pragma unroll 8
    for (int i = 0; i < 128; ++i) s += p[i];
    *o = s;
  }
}

extern "C" void kernel_launch(void* const* d_in, const int* in_sizes, int n_in,
                              void* d_out, int out_size, void* d_ws, size_t ws_size,
                              hipStream_t stream) {
  const int*   inputs = (const int*)d_in[0];
  const float* emb    = (const float*)d_in[1];
  const float* w_Wih  = (const float*)d_in[2];
  const float* w_Whh  = (const float*)d_in[3];
  const float* w_bih  = (const float*)d_in[4];
  const float* w_bhh  = (const float*)d_in[5];
  const float* s_Wih  = (const float*)d_in[6];
  const float* s_Whh  = (const float*)d_in[7];
  const float* s_bih  = (const float*)d_in[8];
  const float* s_bhh  = (const float*)d_in[9];
  const float* r_Wih  = (const float*)d_in[10];
  const float* r_Whh  = (const float*)d_in[11];
  const float* r_bih  = (const float*)d_in[12];
  const float* r_bhh  = (const float*)d_in[13];
  const float* rfc_W1 = (const float*)d_in[14];
  const float* rfc_b1 = (const float*)d_in[15];
  const float* rfc_W2 = (const float*)d_in[16];
  const float* rfc_b2 = (const float*)d_in[17];
  const float* pfc_W1 = (const float*)d_in[18];
  const float* pfc_b1 = (const float*)d_in[19];
  const float* pfc_W2 = (const float*)d_in[20];
  const float* pfc_b2 = (const float*)d_in[21];
  float* out = (float*)d_out;

  // ws layout (bytes):
  //   [0, 4718592)         packed bf16 weights: 6 matrices x 393216 elems
  //   [4718592, 6815744)   sent  f32 [2048][256]
  //   [6815744, 6946816)   rev   f32 [128][256]
  //   [6946816, 6955008)   biz   f32 [8][256]
  unsigned short* pw = (unsigned short*)d_ws;
  float* sent = (float*)((char*)d_ws + 4718592);
  float* rev  = (float*)((char*)d_ws + 6815744);
  float* biz  = (float*)((char*)d_ws + 6946816);

  pack_w<<<dim3(192, 6), 256, 0, stream>>>(w_Wih, w_Whh, s_Wih, s_Whh, r_Wih, r_Whh, pw);

  // word level: 2048 sequences, T=32, x via embedding gather
  gru_bi<8><<<256, 256, 0, stream>>>(emb, inputs, pw + (size_t)0 * 393216,
                                     pw + (size_t)1 * 393216, w_bih, w_bhh, sent, 32);
  // sentence level: 128 sequences, T=16
  gru_bi<2><<<64, 256, 0, stream>>>(sent, nullptr, pw + (size_t)2 * 393216,
                                    pw + (size_t)3 * 393216, s_bih, s_bhh, rev, 16);
  // review level: 8 sequences, T=16
  gru_bi<1><<<8, 256, 0, stream>>>(rev, nullptr, pw + (size_t)4 * 393216,
                                   pw + (size_t)5 * 393216, r_bih, r_bhh, biz, 16);

  fc_head<<<136, 128, 0, stream>>>(rev, biz, rfc_W1, rfc_b1, rfc_W2, rfc_b2,
                                   pfc_W1, pfc_b1, pfc_W2, pfc_b2, out);
}

// Round 2
// 2353.629 us; speedup vs baseline: 1.4255x; 1.4255x over previous
//
#include <hip/hip_runtime.h>

typedef __attribute__((ext_vector_type(8))) unsigned short ushort8;
typedef __attribute__((ext_vector_type(8))) short bf16x8;
typedef __attribute__((ext_vector_type(4))) float f32x4;

__device__ __forceinline__ float bf2f(unsigned short u) {
  union { unsigned int i; float f; } v; v.i = ((unsigned int)u) << 16; return v.f;
}
__device__ __forceinline__ unsigned short f2bf(float f) {
  union { float f; unsigned int i; } v; v.f = f;
  unsigned int x = v.i;
  return (unsigned short)((x + 0x7fffu + ((x >> 16) & 1u)) >> 16);
}
__device__ __forceinline__ float sigm(float x) { return 1.f / (1.f + __expf(-x)); }

// ---------------------------------------------------------------------------
// Pack 6 weight matrices [2][768][256] f32 into MFMA B-fragment order (bf16):
// elem offset = ((((mat*2+dir)*48 + nt)*8 + ks)*64 + l)*8 + e
//   value = W[mat][dir][g = nt*16 + (l&15)][k = ks*32 + (l>>4)*8 + e]
// So per (nt,ks) a wave's 64 lanes load 16B each, contiguous 1KB.
// ---------------------------------------------------------------------------
__global__ __launch_bounds__(256) void pack_mfma(
    const float* __restrict__ s0, const float* __restrict__ s1,
    const float* __restrict__ s2, const float* __restrict__ s3,
    const float* __restrict__ s4, const float* __restrict__ s5,
    unsigned short* __restrict__ dst) {
  const float* srcs[6] = {s0, s1, s2, s3, s4, s5};
  int gid = blockIdx.x * 256 + threadIdx.x;  // 294912 total, exact
  int mat = gid / 49152;
  int rem = gid - mat * 49152;
  int dir = rem / 24576;
  int rem2 = rem - dir * 24576;
  int nt = rem2 / 512;
  int rem3 = rem2 - nt * 512;
  int ks = rem3 >> 6;
  int l = rem3 & 63;
  int g = nt * 16 + (l & 15);
  int k0 = ks * 32 + (l >> 4) * 8;
  const float* sp = srcs[mat] + ((size_t)dir * 768 + g) * 256 + k0;
  ushort8 o;
#pragma unroll
  for (int e = 0; e < 8; ++e) o[e] = f2bf(sp[e]);
  *(ushort8*)(dst + (size_t)gid * 8) = o;
}

// ---------------------------------------------------------------------------
// MFMA bidirectional GRU, one direction per block, MROWS = MT*16 rows/block.
// 512 threads = 8 waves; wave w owns gate columns [32w, 32w+32) in each of
// the r/z/n regions (q=0,1 -> 16-col tiles 2w+q).  h carry kept in f32 regs;
// LDS holds bf16 x and h tiles (XOR-swizzled) feeding ds_read_b128 A-frags.
// MODE 0: xa=f32 emb, rows via idx.  MODE 1: xa,xb bf16 pair (summed).
// MODE 2: xa,xb f32 pair (summed).  OUTF32: f32 out else bf16.
// out layout: out + dir*Mv*256 + n*256 + j.
// ---------------------------------------------------------------------------
template <int MODE, int MT, bool OUTF32>
__global__ __launch_bounds__(512) void gru_mfma(
    const void* __restrict__ xa_, const void* __restrict__ xb_,
    const int* __restrict__ idx,
    const unsigned short* __restrict__ pWih, const unsigned short* __restrict__ pWhh,
    const float* __restrict__ bih, const float* __restrict__ bhh,
    void* __restrict__ out_, int T, int Mv) {
  constexpr int ROWS = MT * 16;
  constexpr int CPR = 32 / MT;  // staging threads per row
  __shared__ __align__(16) char smem[2 * ROWS * 512];
  char* sxp = smem;
  char* shp = smem + ROWS * 512;

  const int tid = threadIdx.x;
  const int w = tid >> 6;
  const int l = tid & 63;
  const int l15 = l & 15;
  const int hi16 = (l >> 4) << 4;
  const int hi4 = (l >> 4) << 2;
  const int w32 = w * 32;
  const int dir = blockIdx.x & 1;
  const int rg = blockIdx.x >> 1;
  const int n0 = rg * ROWS;

  // zero h tile
  for (int v = tid; v < ROWS * 128; v += 512) ((unsigned int*)shp)[v] = 0u;

  // biases per lane (j = w32 + 16q + l15)
  float bR[2], bZ[2], bNX[2], bNH[2];
#pragma unroll
  for (int q = 0; q < 2; ++q) {
    int jj = w32 + 16 * q + l15;
    bR[q] = bih[dir * 768 + jj] + bhh[dir * 768 + jj];
    bZ[q] = bih[dir * 768 + 256 + jj] + bhh[dir * 768 + 256 + jj];
    bNX[q] = bih[dir * 768 + 512 + jj];
    bNH[q] = bhh[dir * 768 + 512 + jj];
  }

  const unsigned short* pih = pWih + (size_t)dir * 196608;
  const unsigned short* phh = pWhh + (size_t)dir * 196608;

  float hreg[MT][2][4];
#pragma unroll
  for (int mt = 0; mt < MT; ++mt)
#pragma unroll
    for (int q = 0; q < 2; ++q)
#pragma unroll
      for (int r = 0; r < 4; ++r) hreg[mt][q][r] = 0.f;

  const int swzA = (l15 & 15) << 4;  // A-frag row = mt*16 + l15; (row&15)=l15

  for (int t = 0; t < T; ++t) {
    // ---- write h(t) to LDS (skip t=0: zeros already there) ----
    if (t > 0) {
#pragma unroll
      for (int mt = 0; mt < MT; ++mt)
#pragma unroll
        for (int q = 0; q < 2; ++q)
#pragma unroll
          for (int r = 0; r < 4; ++r) {
            int i = mt * 16 + hi4 + r;
            int jj = w32 + 16 * q + l15;
            *(unsigned short*)(shp + i * 512 + ((jj * 2) ^ ((i & 15) << 4))) =
                f2bf(hreg[mt][q][r]);
          }
    }
    // ---- stage x(t) ----
    {
      const int row = tid / CPR;
      const int ch = tid - row * CPR;
      const int tt = dir ? (T - 1 - t) : t;
      int n = n0 + row;
      if (n > Mv - 1) n = Mv - 1;
      const int grow = (MODE == 0) ? idx[n * T + tt] : (n * T + tt);
      const int eoff = ch * (8 * MT);
      const int swzr = (row & 15) << 4;
      char* db = sxp + row * 512;
#pragma unroll
      for (int s = 0; s < MT; ++s) {
        float v[8];
        if (MODE == 0) {
          const float4* sp = (const float4*)((const float*)xa_ + (size_t)grow * 256 + eoff + s * 8);
          float4 a = sp[0], b = sp[1];
          v[0] = a.x; v[1] = a.y; v[2] = a.z; v[3] = a.w;
          v[4] = b.x; v[5] = b.y; v[6] = b.z; v[7] = b.w;
        } else if (MODE == 1) {
          ushort8 ua = *(const ushort8*)((const unsigned short*)xa_ + (size_t)grow * 256 + eoff + s * 8);
          ushort8 ub = *(const ushort8*)((const unsigned short*)xb_ + (size_t)grow * 256 + eoff + s * 8);
#pragma unroll
          for (int e = 0; e < 8; ++e) v[e] = bf2f(ua[e]) + bf2f(ub[e]);
        } else {
          const float4* pa = (const float4*)((const float*)xa_ + (size_t)grow * 256 + eoff + s * 8);
          const float4* pb = (const float4*)((const float*)xb_ + (size_t)grow * 256 + eoff + s * 8);
          float4 a = pa[0], a2 = pa[1], b = pb[0], b2 = pb[1];
          v[0] = a.x + b.x; v[1] = a.y + b.y; v[2] = a.z + b.z; v[3] = a.w + b.w;
          v[4] = a2.x + b2.x; v[5] = a2.y + b2.y; v[6] = a2.z + b2.z; v[7] = a2.w + b2.w;
        }
        ushort8 o;
#pragma unroll
        for (int e = 0; e < 8; ++e) o[e] = f2bf(v[e]);
        *(ushort8*)(db + ((eoff * 2 + s * 16) ^ swzr)) = o;
      }
    }
    __syncthreads();

    // ---- two q-passes: MFMA over K=256 (8 ks), then gate epilogue ----
#pragma unroll
    for (int q = 0; q < 2; ++q) {
      f32x4 aR[MT], aZ[MT], aNX[MT], aNH[MT];
#pragma unroll
      for (int mt = 0; mt < MT; ++mt) {
        aR[mt] = (f32x4){bR[q], bR[q], bR[q], bR[q]};
        aZ[mt] = (f32x4){bZ[q], bZ[q], bZ[q], bZ[q]};
        aNX[mt] = (f32x4){bNX[q], bNX[q], bNX[q], bNX[q]};
        aNH[mt] = (f32x4){bNH[q], bNH[q], bNH[q], bNH[q]};
      }
      const int ntR = 2 * w + q;
      const unsigned short* pR = pih + (size_t)ntR * 4096;
      const unsigned short* hR = phh + (size_t)ntR * 4096;
#pragma unroll
      for (int ks = 0; ks < 8; ++ks) {
        const int koff = ks * 64 + hi16;
        bf16x8 ax[MT], ah[MT];
#pragma unroll
        for (int mt = 0; mt < MT; ++mt) {
          const int rb = (mt * 16 + l15) * 512;
          ax[mt] = *(const bf16x8*)(sxp + rb + (koff ^ swzA));
          ah[mt] = *(const bf16x8*)(shp + rb + (koff ^ swzA));
        }
        const int bo = ks * 512 + l * 8;
        bf16x8 bxR = *(const bf16x8*)(pR + bo);
        bf16x8 bxZ = *(const bf16x8*)(pR + 16 * 4096 + bo);
        bf16x8 bxN = *(const bf16x8*)(pR + 32 * 4096 + bo);
        bf16x8 bhR = *(const bf16x8*)(hR + bo);
        bf16x8 bhZ = *(const bf16x8*)(hR + 16 * 4096 + bo);
        bf16x8 bhN = *(const bf16x8*)(hR + 32 * 4096 + bo);
#pragma unroll
        for (int mt = 0; mt < MT; ++mt) {
          aR[mt] = __builtin_amdgcn_mfma_f32_16x16x32_bf16(ax[mt], bxR, aR[mt], 0, 0, 0);
          aR[mt] = __builtin_amdgcn_mfma_f32_16x16x32_bf16(ah[mt], bhR, aR[mt], 0, 0, 0);
          aZ[mt] = __builtin_amdgcn_mfma_f32_16x16x32_bf16(ax[mt], bxZ, aZ[mt], 0, 0, 0);
          aZ[mt] = __builtin_amdgcn_mfma_f32_16x16x32_bf16(ah[mt], bhZ, aZ[mt], 0, 0, 0);
          aNX[mt] = __builtin_amdgcn_mfma_f32_16x16x32_bf16(ax[mt], bxN, aNX[mt], 0, 0, 0);
          aNH[mt] = __builtin_amdgcn_mfma_f32_16x16x32_bf16(ah[mt], bhN, aNH[mt], 0, 0, 0);
        }
      }
      // gate epilogue (f32 carry in hreg)
#pragma unroll
      for (int mt = 0; mt < MT; ++mt)
#pragma unroll
        for (int r = 0; r < 4; ++r) {
          float rr = sigm(aR[mt][r]);
          float zz = sigm(aZ[mt][r]);
          float nv = aNX[mt][r] + rr * aNH[mt][r];
          float e2 = __expf(-2.f * nv);
          float nn = (1.f - e2) / (1.f + e2);
          float hp = hreg[mt][q][r];
          hreg[mt][q][r] = (1.f - zz) * nn + zz * hp;
        }
    }
    __syncthreads();  // all reads of sx/sh done before next step's writes
  }

  // ---- write final hidden ----
#pragma unroll
  for (int mt = 0; mt < MT; ++mt)
#pragma unroll
    for (int q = 0; q < 2; ++q)
#pragma unroll
      for (int r = 0; r < 4; ++r) {
        int i = mt * 16 + hi4 + r;
        int gi = n0 + i;
        if (gi < Mv) {
          int jj = w32 + 16 * q + l15;
          size_t off = (size_t)dir * Mv * 256 + (size_t)gi * 256 + jj;
          if (OUTF32)
            ((float*)out_)[off] = hreg[mt][q][r];
          else
            ((unsigned short*)out_)[off] = f2bf(hreg[mt][q][r]);
        }
      }
}

// ---------------------------------------------------------------------------
// FC heads.  blocks 0..127: r_stars from (rev_f+rev_b) rows (f32 pairs);
// blocks 128..135: b_stars from (biz_f+biz_b).  Linear(256->128)->SELU->Linear.
// ---------------------------------------------------------------------------
__global__ __launch_bounds__(128) void fc_head(
    const float* __restrict__ revf, const float* __restrict__ revb,
    const float* __restrict__ bizf, const float* __restrict__ bizb,
    const float* __restrict__ rW1, const float* __restrict__ rb1,
    const float* __restrict__ rW2, const float* __restrict__ rb2,
    const float* __restrict__ pW1, const float* __restrict__ pb1,
    const float* __restrict__ pW2, const float* __restrict__ pb2,
    float* __restrict__ out) {
  const int b = blockIdx.x;
  const int tid = threadIdx.x;
  const float *xf, *xb2, *W1, *b1, *W2, *b2;
  float* o;
  if (b < 128) {
    xf = revf + (size_t)b * 256; xb2 = revb + (size_t)b * 256;
    W1 = rW1; b1 = rb1; W2 = rW2; b2 = rb2; o = out + 8 + b;
  } else {
    int bb = b - 128;
    xf = bizf + (size_t)bb * 256; xb2 = bizb + (size_t)bb * 256;
    W1 = pW1; b1 = pb1; W2 = pW2; b2 = pb2; o = out + bb;
  }
  float acc = 0.f;
  const float4* f4 = (const float4*)xf;
  const float4* g4 = (const float4*)xb2;
  const float4* w4 = (const float4*)(W1 + (size_t)tid * 256);
#pragma unroll 4
  for (int k = 0; k < 64; ++k) {
    float4 a = f4[k], g = g4[k], w = w4[k];
    acc = fmaf(a.x + g.x, w.x, fmaf(a.y + g.y, w.y,
          fmaf(a.z + g.z, w.z, fmaf(a.w + g.w, w.w, acc))));
  }
  acc += b1[tid];
  const float LAM = 1.0507009873554805f, ALPHA = 1.6732632423543772f;
  float h = acc > 0.f ? LAM * acc : LAM * ALPHA * (__expf(acc) - 1.f);
  __shared__ float p[128];
  p[tid] = h * W2[tid];
  __syncthreads();
  if (tid == 0) {
    float s = b2[0];
#pragma unroll 8
    for (int i = 0; i < 128; ++i) s += p[i];
    *o = s;
  }
}

extern "C" void kernel_launch(void* const* d_in, const int* in_sizes, int n_in,
                              void* d_out, int out_size, void* d_ws, size_t ws_size,
                              hipStream_t stream) {
  const int*   inputs = (const int*)d_in[0];
  const float* emb    = (const float*)d_in[1];
  const float* w_Wih  = (const float*)d_in[2];
  const float* w_Whh  = (const float*)d_in[3];
  const float* w_bih  = (const float*)d_in[4];
  const float* w_bhh  = (const float*)d_in[5];
  const float* s_Wih  = (const float*)d_in[6];
  const float* s_Whh  = (const float*)d_in[7];
  const float* s_bih  = (const float*)d_in[8];
  const float* s_bhh  = (const float*)d_in[9];
  const float* r_Wih  = (const float*)d_in[10];
  const float* r_Whh  = (const float*)d_in[11];
  const float* r_bih  = (const float*)d_in[12];
  const float* r_bhh  = (const float*)d_in[13];
  const float* rfc_W1 = (const float*)d_in[14];
  const float* rfc_b1 = (const float*)d_in[15];
  const float* rfc_W2 = (const float*)d_in[16];
  const float* rfc_b2 = (const float*)d_in[17];
  const float* pfc_W1 = (const float*)d_in[18];
  const float* pfc_b1 = (const float*)d_in[19];
  const float* pfc_W2 = (const float*)d_in[20];
  const float* pfc_b2 = (const float*)d_in[21];
  float* out = (float*)d_out;

  // ws layout (bytes):
  //   [0, 4718592)          packed bf16 weights, 6 mats x 786432 B
  //   [4718592, 5767168)    sent_f bf16 [2048][256]
  //   [5767168, 6815744)    sent_b bf16 [2048][256]   (contiguous after sent_f)
  //   [6815744, 6946816)    rev_f  f32 [128][256]
  //   [6946816, 7077888)    rev_b  f32 [128][256]
  //   [7077888, 7086080)    biz_f  f32 [8][256]
  //   [7086080, 7094272)    biz_b  f32 [8][256]
  unsigned short* pmf = (unsigned short*)d_ws;
  unsigned short* sent_f = (unsigned short*)((char*)d_ws + 4718592);
  float* rev_f = (float*)((char*)d_ws + 6815744);
  float* biz_f = (float*)((char*)d_ws + 7077888);
  float* rev_b = (float*)((char*)d_ws + 6946816);
  float* biz_b = (float*)((char*)d_ws + 7086080);

  pack_mfma<<<1152, 256, 0, stream>>>(w_Wih, w_Whh, s_Wih, s_Whh, r_Wih, r_Whh, pmf);

  // word: M=2048, T=32, 32 row-groups x 2 dirs
  gru_mfma<0, 4, false><<<64, 512, 0, stream>>>(
      emb, nullptr, inputs, pmf, pmf + 393216, w_bih, w_bhh, sent_f, 32, 2048);
  // sentence: M=128, T=16, bf16 pair input
  gru_mfma<1, 4, true><<<4, 512, 0, stream>>>(
      sent_f, sent_f + 2048 * 256, nullptr, pmf + 2 * 393216, pmf + 3 * 393216,
      s_bih, s_bhh, rev_f, 16, 128);
  // review: M=8 (padded to 16), T=16, f32 pair input
  gru_mfma<2, 1, true><<<2, 512, 0, stream>>>(
      rev_f, rev_b, nullptr, pmf + 4 * 393216, pmf + 5 * 393216,
      r_bih, r_bhh, biz_f, 16, 8);

  fc_head<<<136, 128, 0, stream>>>(rev_f, rev_b, biz_f, biz_b,
                                   rfc_W1, rfc_b1, rfc_W2, rfc_b2,
                                   pfc_W1, pfc_b1, pfc_W2, pfc_b2, out);
}

// Round 3
// 1228.815 us; speedup vs baseline: 2.7303x; 1.9154x over previous
//
#include <hip/hip_runtime.h>

typedef unsigned short ushort;
typedef __attribute__((ext_vector_type(8))) unsigned short ushort8;
typedef __attribute__((ext_vector_type(4))) unsigned short ushort4v;
typedef __attribute__((ext_vector_type(8))) short bf16x8;
typedef __attribute__((ext_vector_type(4))) float f32x4;

__device__ __forceinline__ float bf2f(ushort u) {
  union { unsigned int i; float f; } v; v.i = ((unsigned int)u) << 16; return v.f;
}
__device__ __forceinline__ ushort f2bf(float f) {
  union { float f; unsigned int i; } v; v.f = f;
  unsigned int x = v.i;
  return (ushort)((x + 0x7fffu + ((x >> 16) & 1u)) >> 16);
}
__device__ __forceinline__ float sigm(float x) { return 1.f / (1.f + __expf(-x)); }

// ---------------------------------------------------------------------------
// pack 6 weight matrices [2][768][256] f32 -> MFMA B-frag order bf16:
// elem = ((((mat*2+dir)*48 + ntAll)*8 + ks)*64 + l)*8 + e
//      = W[mat][dir][g = ntAll*16 + (l&15)][k = ks*32 + (l>>4)*8 + e]
// (verified by R1/R2 absmax pass)
// ---------------------------------------------------------------------------
__global__ __launch_bounds__(256) void pack_mfma(
    const float* __restrict__ s0, const float* __restrict__ s1,
    const float* __restrict__ s2, const float* __restrict__ s3,
    const float* __restrict__ s4, const float* __restrict__ s5,
    ushort* __restrict__ dst) {
  const float* srcs[6] = {s0, s1, s2, s3, s4, s5};
  int gid = blockIdx.x * 256 + threadIdx.x;  // 294912 total
  int mat = gid / 49152;
  int rem = gid - mat * 49152;
  int dir = rem / 24576;
  int rem2 = rem - dir * 24576;
  int nt = rem2 / 512;
  int rem3 = rem2 - nt * 512;
  int ks = rem3 >> 6;
  int l = rem3 & 63;
  int g = nt * 16 + (l & 15);
  int k0 = ks * 32 + (l >> 4) * 8;
  const float* sp = srcs[mat] + ((size_t)dir * 768 + g) * 256 + k0;
  ushort8 o;
#pragma unroll
  for (int e = 0; e < 8; ++e) o[e] = f2bf(sp[e]);
  *(ushort8*)(dst + (size_t)gid * 8) = o;
}

// emb f32 [30000*256] -> bf16
__global__ __launch_bounds__(256) void embcvt(const float* __restrict__ src,
                                              ushort* __restrict__ dst) {
  int i = blockIdx.x * 256 + threadIdx.x;  // 960000 vecs of 8
  if (i >= 960000) return;
  const float4* s = (const float4*)(src + (size_t)i * 8);
  float4 a = s[0], b = s[1];
  ushort8 o;
  o[0] = f2bf(a.x); o[1] = f2bf(a.y); o[2] = f2bf(a.z); o[3] = f2bf(a.w);
  o[4] = f2bf(b.x); o[5] = f2bf(b.y); o[6] = f2bf(b.z); o[7] = f2bf(b.w);
  *(ushort8*)(dst + (size_t)i * 8) = o;
}

// bf16 + bf16 -> bf16 (8-wide)
__global__ __launch_bounds__(256) void sum2bb(const ushort* __restrict__ a,
                                              const ushort* __restrict__ b,
                                              ushort* __restrict__ o, int nvec) {
  int i = blockIdx.x * 256 + threadIdx.x;
  if (i >= nvec) return;
  ushort8 va = *(const ushort8*)(a + (size_t)i * 8);
  ushort8 vb = *(const ushort8*)(b + (size_t)i * 8);
  ushort8 r;
#pragma unroll
  for (int e = 0; e < 8; ++e) r[e] = f2bf(bf2f(va[e]) + bf2f(vb[e]));
  *(ushort8*)(o + (size_t)i * 8) = r;
}

// f32 + f32 -> bf16 (8-wide)
__global__ __launch_bounds__(256) void sum2fb(const float* __restrict__ a,
                                              const float* __restrict__ b,
                                              ushort* __restrict__ o, int nvec) {
  int i = blockIdx.x * 256 + threadIdx.x;
  if (i >= nvec) return;
  const float4* pa = (const float4*)(a + (size_t)i * 8);
  const float4* pb = (const float4*)(b + (size_t)i * 8);
  float4 a0 = pa[0], a1 = pa[1], b0 = pb[0], b1 = pb[1];
  ushort8 r;
  r[0] = f2bf(a0.x + b0.x); r[1] = f2bf(a0.y + b0.y);
  r[2] = f2bf(a0.z + b0.z); r[3] = f2bf(a0.w + b0.w);
  r[4] = f2bf(a1.x + b1.x); r[5] = f2bf(a1.y + b1.y);
  r[6] = f2bf(a1.z + b1.z); r[7] = f2bf(a1.w + b1.w);
  *(ushort8*)(o + (size_t)i * 8) = r;
}

// ---------------------------------------------------------------------------
// gx GEMM: C[row'][col'] = sum_k A[src(row')][k] * W[col'][k], written in
// per-16x16-tile C-frag lane order: gx[dir][tid_m][tid_n][lane][rr] (ushort).
// row' is t-major: t = row'/NPAD, n = row'%NPAD + noff.
// MODE 0: src row = idx[n*T + t] into A (emb bf16).  MODE 1: src row =
// min(n,NSEQ-1)*T + t into A.  Tile: BM=128, BN=128 (8 col-tiles), K=256.
// 256 threads, 4 waves (2x2).  A staged in LDS (2-bit XOR chunk swizzle),
// B-frags direct from L2 (packed layout above), both prefetch-pipelined.
// ---------------------------------------------------------------------------
template <int MODE, bool NT>
__global__ __launch_bounds__(256) void gemm_gx(
    const ushort* __restrict__ A, const int* __restrict__ idx,
    const ushort* __restrict__ B, ushort* __restrict__ gx,
    int NPAD, int NSEQ, int T, int noff, int TMloc) {
  __shared__ __align__(16) ushort sa[128 * 32];
  const int tid = threadIdx.x;
  const int bm = blockIdx.x, bn = blockIdx.y;
  const int w = tid >> 6, l = tid & 63;
  const int wr = w >> 1, wc = w & 1;
  const int l15 = l & 15, lc = l >> 4;

  // staging: thread -> row srow, 2 chunks (16B each)
  const int srow = tid >> 1;
  const int c0 = (tid & 1) * 2;
  int rloc = bm * 128 + srow;
  int t = rloc / NPAD;
  int nl = rloc - t * NPAD;
  int n = nl + noff;
  int grow;
  if (MODE == 0) grow = idx[n * T + t];
  else { int nn = n < NSEQ ? n : NSEQ - 1; grow = nn * T + t; }
  const ushort* srcrow = A + (size_t)grow * 256;

  // B column tiles for this wave
  const ushort* bbase[4];
#pragma unroll
  for (int i = 0; i < 4; ++i) {
    int ct = bn * 8 + wc * 4 + i;
    int dir = ct / 48;
    int ntAll = ct - dir * 48;
    bbase[i] = B + ((size_t)(dir * 48 + ntAll) * 8) * 512 + l * 8;
  }

  f32x4 acc[4][4];
#pragma unroll
  for (int mt = 0; mt < 4; ++mt)
#pragma unroll
    for (int nt = 0; nt < 4; ++nt) acc[mt][nt] = (f32x4){0.f, 0.f, 0.f, 0.f};

  ushort8 sta[2];
  bf16x8 bcur[4], bnxt[4];
#pragma unroll
  for (int j = 0; j < 2; ++j)
    sta[j] = *(const ushort8*)(srcrow + (c0 + j) * 8);
#pragma unroll
  for (int i = 0; i < 4; ++i) bcur[i] = *(const bf16x8*)(bbase[i]);

#pragma unroll
  for (int kk = 0; kk < 8; ++kk) {
    __syncthreads();
    *(ushort8*)(sa + srow * 32 + ((c0 + 0) ^ (srow & 3)) * 8) = sta[0];
    *(ushort8*)(sa + srow * 32 + ((c0 + 1) ^ (srow & 3)) * 8) = sta[1];
    __syncthreads();
    if (kk < 7) {
#pragma unroll
      for (int j = 0; j < 2; ++j)
        sta[j] = *(const ushort8*)(srcrow + (kk + 1) * 32 + (c0 + j) * 8);
#pragma unroll
      for (int i = 0; i < 4; ++i)
        bnxt[i] = *(const bf16x8*)(bbase[i] + (kk + 1) * 512);
    }
    bf16x8 af[4];
#pragma unroll
    for (int mt = 0; mt < 4; ++mt) {
      int row = wr * 64 + mt * 16 + l15;
      af[mt] = *(const bf16x8*)(sa + row * 32 + (lc ^ (row & 3)) * 8);
    }
#pragma unroll
    for (int mt = 0; mt < 4; ++mt)
#pragma unroll
      for (int nt = 0; nt < 4; ++nt)
        acc[mt][nt] = __builtin_amdgcn_mfma_f32_16x16x32_bf16(af[mt], bcur[nt],
                                                              acc[mt][nt], 0, 0, 0);
#pragma unroll
    for (int i = 0; i < 4; ++i) bcur[i] = bnxt[i];
  }

  // epilogue: per (mt,nt) tile, lane writes its 4 values (rows hi4+0..3)
#pragma unroll
  for (int mt = 0; mt < 4; ++mt) {
    int tid_m = bm * 8 + wr * 4 + mt;
#pragma unroll
    for (int nt = 0; nt < 4; ++nt) {
      int ct = bn * 8 + wc * 4 + nt;
      int dir = ct / 48;
      int tid_n = ct - dir * 48;
      ushort4v o;
      o[0] = f2bf(acc[mt][nt][0]); o[1] = f2bf(acc[mt][nt][1]);
      o[2] = f2bf(acc[mt][nt][2]); o[3] = f2bf(acc[mt][nt][3]);
      ushort4v* dst = (ushort4v*)(gx + (((size_t)dir * TMloc + tid_m) * 48 + tid_n) * 256 + l * 4);
      if (NT) __builtin_nontemporal_store(o, dst);
      else *dst = o;
    }
  }
}

// ---------------------------------------------------------------------------
// Word recurrent: 512 thr = 8 waves, 64 rows/block, one dir/block, streams
// Whh B-frags from L2 each step; gx read nontemporal in C-frag order.
// ---------------------------------------------------------------------------
__global__ __launch_bounds__(512) void gru_word(
    const ushort* __restrict__ gx, const ushort* __restrict__ pWhh,
    const float* __restrict__ bih, const float* __restrict__ bhh,
    ushort* __restrict__ out, int T, int NSEQ, int TPT, int TMloc, int noff) {
  constexpr int MT = 4;
  __shared__ __align__(16) char shp[64 * 512];
  const int tid = threadIdx.x;
  const int w = tid >> 6, l = tid & 63;
  const int l15 = l & 15, lc = l >> 4;
  const int hi4 = lc << 2;
  const int dir = blockIdx.x & 1;
  const int rg = blockIdx.x >> 1;
  const int n0l = rg * 64;

  for (int v = tid; v < 64 * 128; v += 512) ((unsigned int*)shp)[v] = 0u;

  float bR[2], bZ[2], bNX[2], bNH[2];
#pragma unroll
  for (int q = 0; q < 2; ++q) {
    int jj = (2 * w + q) * 16 + l15;
    bR[q] = bih[dir * 768 + jj] + bhh[dir * 768 + jj];
    bZ[q] = bih[dir * 768 + 256 + jj] + bhh[dir * 768 + 256 + jj];
    bNX[q] = bih[dir * 768 + 512 + jj];
    bNH[q] = bhh[dir * 768 + 512 + jj];
  }
  const ushort* ph = pWhh + (size_t)dir * 196608;
  const size_t gxd = (size_t)dir * TMloc * 48 * 256;

  float hreg[MT][2][4];
#pragma unroll
  for (int mt = 0; mt < MT; ++mt)
#pragma unroll
    for (int q = 0; q < 2; ++q)
#pragma unroll
      for (int r = 0; r < 4; ++r) hreg[mt][q][r] = 0.f;

  for (int t = 0; t < T; ++t) {
    const int tt = dir ? (T - 1 - t) : t;
    // gx prefetch (nontemporal, C-frag order)
    ushort4v gq[2][3][MT];
#pragma unroll
    for (int q = 0; q < 2; ++q)
#pragma unroll
      for (int g = 0; g < 3; ++g)
#pragma unroll
        for (int mt = 0; mt < MT; ++mt) {
          int tile = tt * TPT + (n0l >> 4) + mt;
          int tn = g * 16 + 2 * w + q;
          gq[q][g][mt] = __builtin_nontemporal_load(
              (const ushort4v*)(gx + gxd + ((size_t)tile * 48 + tn) * 256 + l * 4));
        }
    if (t > 0) {
#pragma unroll
      for (int mt = 0; mt < MT; ++mt)
#pragma unroll
        for (int q = 0; q < 2; ++q)
#pragma unroll
          for (int r = 0; r < 4; ++r) {
            int i = mt * 16 + hi4 + r;
            int jj = (2 * w + q) * 16 + l15;
            *(ushort*)(shp + i * 512 + ((jj * 2) ^ ((i & 15) << 4))) =
                f2bf(hreg[mt][q][r]);
          }
    }
    __syncthreads();

    f32x4 aR[2][MT], aZ[2][MT], aNH[2][MT];
#pragma unroll
    for (int q = 0; q < 2; ++q)
#pragma unroll
      for (int mt = 0; mt < MT; ++mt) {
        aR[q][mt] = (f32x4){bR[q], bR[q], bR[q], bR[q]};
        aZ[q][mt] = (f32x4){bZ[q], bZ[q], bZ[q], bZ[q]};
        aNH[q][mt] = (f32x4){bNH[q], bNH[q], bNH[q], bNH[q]};
      }
#pragma unroll
    for (int ks = 0; ks < 8; ++ks) {
      bf16x8 af[MT];
#pragma unroll
      for (int mt = 0; mt < MT; ++mt) {
        int row = mt * 16 + l15;
        af[mt] = *(const bf16x8*)(shp + row * 512 + ((ks * 64 + lc * 16) ^ (l15 << 4)));
      }
#pragma unroll
      for (int q = 0; q < 2; ++q) {
        int ntR = 2 * w + q;
        const ushort* pb = ph + ((ntR * 8 + ks) * 512) + l * 8;
        bf16x8 bRw = *(const bf16x8*)(pb);
        bf16x8 bZw = *(const bf16x8*)(pb + 65536);
        bf16x8 bNw = *(const bf16x8*)(pb + 131072);
#pragma unroll
        for (int mt = 0; mt < MT; ++mt) {
          aR[q][mt] = __builtin_amdgcn_mfma_f32_16x16x32_bf16(af[mt], bRw, aR[q][mt], 0, 0, 0);
          aZ[q][mt] = __builtin_amdgcn_mfma_f32_16x16x32_bf16(af[mt], bZw, aZ[q][mt], 0, 0, 0);
          aNH[q][mt] = __builtin_amdgcn_mfma_f32_16x16x32_bf16(af[mt], bNw, aNH[q][mt], 0, 0, 0);
        }
      }
    }
#pragma unroll
    for (int q = 0; q < 2; ++q)
#pragma unroll
      for (int mt = 0; mt < MT; ++mt)
#pragma unroll
        for (int r = 0; r < 4; ++r) {
          float rr = sigm(aR[q][mt][r] + bf2f(gq[q][0][mt][r]));
          float zz = sigm(aZ[q][mt][r] + bf2f(gq[q][1][mt][r]));
          float nv = bf2f(gq[q][2][mt][r]) + bNX[q] + rr * aNH[q][mt][r];
          float e2 = __expf(-2.f * nv);
          float nn = (1.f - e2) / (1.f + e2);
          hreg[mt][q][r] = (1.f - zz) * nn + zz * hreg[mt][q][r];
        }
    __syncthreads();
  }

#pragma unroll
  for (int mt = 0; mt < MT; ++mt)
#pragma unroll
    for (int q = 0; q < 2; ++q)
#pragma unroll
      for (int r = 0; r < 4; ++r) {
        int i = mt * 16 + hi4 + r;
        int gn = noff + n0l + i;
        int jj = (2 * w + q) * 16 + l15;
        out[(size_t)dir * NSEQ * 256 + (size_t)gn * 256 + jj] = f2bf(hreg[mt][q][r]);
      }
}

// ---------------------------------------------------------------------------
// Small recurrent (sent/review): 512 thr, 16 rows/block, r,z weight frags
// cached in registers (loaded once), n-gate streamed.  f32 output.
// ---------------------------------------------------------------------------
__global__ __launch_bounds__(512) void gru_small(
    const ushort* __restrict__ gx, const ushort* __restrict__ pWhh,
    const float* __restrict__ bih, const float* __restrict__ bhh,
    float* __restrict__ out, int T, int NSEQ, int TPT, int TMloc) {
  __shared__ __align__(16) char shp[16 * 512];
  const int tid = threadIdx.x;
  const int w = tid >> 6, l = tid & 63;
  const int l15 = l & 15, lc = l >> 4;
  const int hi4 = lc << 2;
  const int dir = blockIdx.x & 1;
  const int rg = blockIdx.x >> 1;
  const int n0l = rg * 16;

  for (int v = tid; v < 16 * 128; v += 512) ((unsigned int*)shp)[v] = 0u;

  float bR[2], bZ[2], bNX[2], bNH[2];
#pragma unroll
  for (int q = 0; q < 2; ++q) {
    int jj = (2 * w + q) * 16 + l15;
    bR[q] = bih[dir * 768 + jj] + bhh[dir * 768 + jj];
    bZ[q] = bih[dir * 768 + 256 + jj] + bhh[dir * 768 + 256 + jj];
    bNX[q] = bih[dir * 768 + 512 + jj];
    bNH[q] = bhh[dir * 768 + 512 + jj];
  }
  const ushort* ph = pWhh + (size_t)dir * 196608;
  const size_t gxd = (size_t)dir * TMloc * 48 * 256;

  // cache r,z weight fragments (128 VGPR)
  bf16x8 wR[2][8], wZ[2][8];
#pragma unroll
  for (int q = 0; q < 2; ++q)
#pragma unroll
    for (int ks = 0; ks < 8; ++ks) {
      const ushort* pb = ph + (((2 * w + q) * 8 + ks) * 512) + l * 8;
      wR[q][ks] = *(const bf16x8*)(pb);
      wZ[q][ks] = *(const bf16x8*)(pb + 65536);
    }

  float hreg[2][4];
#pragma unroll
  for (int q = 0; q < 2; ++q)
#pragma unroll
    for (int r = 0; r < 4; ++r) hreg[q][r] = 0.f;

  for (int t = 0; t < T; ++t) {
    const int tt = dir ? (T - 1 - t) : t;
    ushort4v gq[2][3];
#pragma unroll
    for (int q = 0; q < 2; ++q)
#pragma unroll
      for (int g = 0; g < 3; ++g) {
        int tile = tt * TPT + rg;
        int tn = g * 16 + 2 * w + q;
        gq[q][g] = *(const ushort4v*)(gx + gxd + ((size_t)tile * 48 + tn) * 256 + l * 4);
      }
    if (t > 0) {
#pragma unroll
      for (int q = 0; q < 2; ++q)
#pragma unroll
        for (int r = 0; r < 4; ++r) {
          int i = hi4 + r;
          int jj = (2 * w + q) * 16 + l15;
          *(ushort*)(shp + i * 512 + ((jj * 2) ^ ((i & 15) << 4))) = f2bf(hreg[q][r]);
        }
    }
    __syncthreads();

    f32x4 aR[2], aZ[2], aNH[2];
#pragma unroll
    for (int q = 0; q < 2; ++q) {
      aR[q] = (f32x4){bR[q], bR[q], bR[q], bR[q]};
      aZ[q] = (f32x4){bZ[q], bZ[q], bZ[q], bZ[q]};
      aNH[q] = (f32x4){bNH[q], bNH[q], bNH[q], bNH[q]};
    }
#pragma unroll
    for (int ks = 0; ks < 8; ++ks) {
      int row = l15;
      bf16x8 af = *(const bf16x8*)(shp + row * 512 + ((ks * 64 + lc * 16) ^ (l15 << 4)));
#pragma unroll
      for (int q = 0; q < 2; ++q) {
        const ushort* pbn = ph + 131072 + (((2 * w + q) * 8 + ks) * 512) + l * 8;
        bf16x8 bNw = *(const bf16x8*)(pbn);
        aR[q] = __builtin_amdgcn_mfma_f32_16x16x32_bf16(af, wR[q][ks], aR[q], 0, 0, 0);
        aZ[q] = __builtin_amdgcn_mfma_f32_16x16x32_bf16(af, wZ[q][ks], aZ[q], 0, 0, 0);
        aNH[q] = __builtin_amdgcn_mfma_f32_16x16x32_bf16(af, bNw, aNH[q], 0, 0, 0);
      }
    }
#pragma unroll
    for (int q = 0; q < 2; ++q)
#pragma unroll
      for (int r = 0; r < 4; ++r) {
        float rr = sigm(aR[q][r] + bf2f(gq[q][0][r]));
        float zz = sigm(aZ[q][r] + bf2f(gq[q][1][r]));
        float nv = bf2f(gq[q][2][r]) + bNX[q] + rr * aNH[q][r];
        float e2 = __expf(-2.f * nv);
        float nn = (1.f - e2) / (1.f + e2);
        hreg[q][r] = (1.f - zz) * nn + zz * hreg[q][r];
      }
    __syncthreads();
  }

#pragma unroll
  for (int q = 0; q < 2; ++q)
#pragma unroll
    for (int r = 0; r < 4; ++r) {
      int i = hi4 + r;
      int gn = n0l + i;
      if (gn < NSEQ) {
        int jj = (2 * w + q) * 16 + l15;
        out[(size_t)dir * NSEQ * 256 + (size_t)gn * 256 + jj] = hreg[q][r];
      }
    }
}

// ---------------------------------------------------------------------------
// FC heads (unchanged, validated R2)
// ---------------------------------------------------------------------------
__global__ __launch_bounds__(128) void fc_head(
    const float* __restrict__ revf, const float* __restrict__ revb,
    const float* __restrict__ bizf, const float* __restrict__ bizb,
    const float* __restrict__ rW1, const float* __restrict__ rb1,
    const float* __restrict__ rW2, const float* __restrict__ rb2,
    const float* __restrict__ pW1, const float* __restrict__ pb1,
    const float* __restrict__ pW2, const float* __restrict__ pb2,
    float* __restrict__ out) {
  const int b = blockIdx.x;
  const int tid = threadIdx.x;
  const float *xf, *xb2, *W1, *b1, *W2, *b2;
  float* o;
  if (b < 128) {
    xf = revf + (size_t)b * 256; xb2 = revb + (size_t)b * 256;
    W1 = rW1; b1 = rb1; W2 = rW2; b2 = rb2; o = out + 8 + b;
  } else {
    int bb = b - 128;
    xf = bizf + (size_t)bb * 256; xb2 = bizb + (size_t)bb * 256;
    W1 = pW1; b1 = pb1; W2 = pW2; b2 = pb2; o = out + bb;
  }
  float acc = 0.f;
  const float4* f4 = (const float4*)xf;
  const float4* g4 = (const float4*)xb2;
  const float4* w4 = (const float4*)(W1 + (size_t)tid * 256);
#pragma unroll 4
  for (int k = 0; k < 64; ++k) {
    float4 a = f4[k], g = g4[k], w = w4[k];
    acc = fmaf(a.x + g.x, w.x, fmaf(a.y + g.y, w.y,
          fmaf(a.z + g.z, w.z, fmaf(a.w + g.w, w.w, acc))));
  }
  acc += b1[tid];
  const float LAM = 1.0507009873554805f, ALPHA = 1.6732632423543772f;
  float h = acc > 0.f ? LAM * acc : LAM * ALPHA * (__expf(acc) - 1.f);
  __shared__ float p[128];
  p[tid] = h * W2[tid];
  __syncthreads();
  if (tid == 0) {
    float s = b2[0];
#pragma unroll 8
    for (int i = 0; i < 128; ++i) s += p[i];
    *o = s;
  }
}

extern "C" void kernel_launch(void* const* d_in, const int* in_sizes, int n_in,
                              void* d_out, int out_size, void* d_ws, size_t ws_size,
                              hipStream_t stream) {
  const int*   inputs = (const int*)d_in[0];
  const float* emb    = (const float*)d_in[1];
  const float* w_Wih  = (const float*)d_in[2];
  const float* w_Whh  = (const float*)d_in[3];
  const float* w_bih  = (const float*)d_in[4];
  const float* w_bhh  = (const float*)d_in[5];
  const float* s_Wih  = (const float*)d_in[6];
  const float* s_Whh  = (const float*)d_in[7];
  const float* s_bih  = (const float*)d_in[8];
  const float* s_bhh  = (const float*)d_in[9];
  const float* r_Wih  = (const float*)d_in[10];
  const float* r_Whh  = (const float*)d_in[11];
  const float* r_bih  = (const float*)d_in[12];
  const float* r_bhh  = (const float*)d_in[13];
  const float* rfc_W1 = (const float*)d_in[14];
  const float* rfc_b1 = (const float*)d_in[15];
  const float* rfc_W2 = (const float*)d_in[16];
  const float* rfc_b2 = (const float*)d_in[17];
  const float* pfc_W1 = (const float*)d_in[18];
  const float* pfc_b1 = (const float*)d_in[19];
  const float* pfc_W2 = (const float*)d_in[20];
  const float* pfc_b2 = (const float*)d_in[21];
  float* out = (float*)d_out;

  // ws layout (bytes):
  char* ws = (char*)d_ws;
  ushort* pmf    = (ushort*)(ws);                    //  4,718,592
  ushort* embb   = (ushort*)(ws + 4718592);          // 15,360,000
  ushort* sentA  = (ushort*)(ws + 20078592);         //  1,048,576
  ushort* sent_f = (ushort*)(ws + 21127168);         //  2,097,152 (both dirs)
  float*  rev_f  = (float*)(ws + 23224320);          //    262,144 (both dirs)
  ushort* revsum = (ushort*)(ws + 23486464);         //     65,536
  float*  biz_f  = (float*)(ws + 23552000);          //     16,384
  ushort* gxs    = (ushort*)(ws + 23568384);         //  6,291,456
  ushort* gxr    = (ushort*)(ws + 29859840);         //    786,432
  ushort* gxw    = (ushort*)(ws + 30646272);         // up to 201,326,592
  float* rev_b = rev_f + 32768;
  float* biz_b = biz_f + 2048;
  ushort* sent_b = sent_f + 524288;

  // word gx pass count to fit ws
  const size_t gx_full = 201326592ull;
  const size_t fixed_end = 30646272ull;
  int NP = 32;
  for (int cand = 1; cand <= 32; cand <<= 1) {
    if (ws_size >= fixed_end + gx_full / cand) { NP = cand; break; }
  }
  const int slice = 2048 / NP;
  const int TMp = 4096 / NP;

  embcvt<<<3750, 256, 0, stream>>>(emb, embb);
  pack_mfma<<<1152, 256, 0, stream>>>(w_Wih, w_Whh, s_Wih, s_Whh, r_Wih, r_Whh, pmf);

  // word level (per pass: gx GEMM then recurrent)
  for (int p = 0; p < NP; ++p) {
    gemm_gx<0, true><<<dim3(512 / NP, 12), 256, 0, stream>>>(
        embb, inputs, pmf, gxw, slice, 2048, 32, p * slice, TMp);
    gru_word<<<(slice / 64) * 2, 512, 0, stream>>>(
        gxw, pmf + 393216, w_bih, w_bhh, sent_f, 32, 2048, slice / 16, TMp, p * slice);
  }
  sum2bb<<<256, 256, 0, stream>>>(sent_f, sent_b, sentA, 65536);

  // sentence level
  gemm_gx<1, false><<<dim3(16, 12), 256, 0, stream>>>(
      sentA, nullptr, pmf + 2 * 393216, gxs, 128, 128, 16, 0, 128);
  gru_small<<<16, 512, 0, stream>>>(gxs, pmf + 3 * 393216, s_bih, s_bhh,
                                    rev_f, 16, 128, 8, 128);
  sum2fb<<<16, 256, 0, stream>>>(rev_f, rev_b, revsum, 4096);

  // review level (seqs padded 8->16)
  gemm_gx<1, false><<<dim3(2, 12), 256, 0, stream>>>(
      revsum, nullptr, pmf + 4 * 393216, gxr, 16, 8, 16, 0, 16);
  gru_small<<<2, 512, 0, stream>>>(gxr, pmf + 5 * 393216, r_bih, r_bhh,
                                   biz_f, 16, 8, 1, 16);

  fc_head<<<136, 128, 0, stream>>>(rev_f, rev_b, biz_f, biz_b,
                                   rfc_W1, rfc_b1, rfc_W2, rfc_b2,
                                   pfc_W1, pfc_b1, pfc_W2, pfc_b2, out);
}

// Round 6
// 511.999 us; speedup vs baseline: 6.5527x; 2.4000x over previous
//
#include <hip/hip_runtime.h>

typedef unsigned short ushort;
typedef __attribute__((ext_vector_type(8))) unsigned short ushort8;
typedef __attribute__((ext_vector_type(4))) unsigned short ushort4v;
typedef __attribute__((ext_vector_type(8))) short bf16x8;
typedef __attribute__((ext_vector_type(4))) float f32x4;

__device__ __forceinline__ float bf2f(ushort u) {
  union { unsigned int i; float f; } v; v.i = ((unsigned int)u) << 16; return v.f;
}
__device__ __forceinline__ ushort f2bf(float f) {
  union { float f; unsigned int i; } v; v.f = f;
  unsigned int x = v.i;
  return (ushort)((x + 0x7fffu + ((x >> 16) & 1u)) >> 16);
}
__device__ __forceinline__ float sigm(float x) { return 1.f / (1.f + __expf(-x)); }

// ---------------------------------------------------------------------------
// pack 6 weight matrices [2][768][256] f32 -> MFMA B-frag order bf16:
// elem = ((((mat*2+dir)*48 + ntAll)*8 + ks)*64 + l)*8 + e
//      = W[mat][dir][g = ntAll*16 + (l&15)][k = ks*32 + (l>>4)*8 + e]
// ---------------------------------------------------------------------------
__global__ __launch_bounds__(256) void pack_mfma(
    const float* __restrict__ s0, const float* __restrict__ s1,
    const float* __restrict__ s2, const float* __restrict__ s3,
    const float* __restrict__ s4, const float* __restrict__ s5,
    ushort* __restrict__ dst) {
  const float* srcs[6] = {s0, s1, s2, s3, s4, s5};
  int gid = blockIdx.x * 256 + threadIdx.x;  // 294912 total
  int mat = gid / 49152;
  int rem = gid - mat * 49152;
  int dir = rem / 24576;
  int rem2 = rem - dir * 24576;
  int nt = rem2 / 512;
  int rem3 = rem2 - nt * 512;
  int ks = rem3 >> 6;
  int l = rem3 & 63;
  int g = nt * 16 + (l & 15);
  int k0 = ks * 32 + (l >> 4) * 8;
  const float* sp = srcs[mat] + ((size_t)dir * 768 + g) * 256 + k0;
  ushort8 o;
#pragma unroll
  for (int e = 0; e < 8; ++e) o[e] = f2bf(sp[e]);
  *(ushort8*)(dst + (size_t)gid * 8) = o;
}

// emb f32 [30000*256] -> bf16
__global__ __launch_bounds__(256) void embcvt(const float* __restrict__ src,
                                              ushort* __restrict__ dst) {
  int i = blockIdx.x * 256 + threadIdx.x;  // 960000 vecs of 8
  if (i >= 960000) return;
  const float4* s = (const float4*)(src + (size_t)i * 8);
  float4 a = s[0], b = s[1];
  ushort8 o;
  o[0] = f2bf(a.x); o[1] = f2bf(a.y); o[2] = f2bf(a.z); o[3] = f2bf(a.w);
  o[4] = f2bf(b.x); o[5] = f2bf(b.y); o[6] = f2bf(b.z); o[7] = f2bf(b.w);
  *(ushort8*)(dst + (size_t)i * 8) = o;
}

// bf16 + bf16 -> bf16 (8-wide)
__global__ __launch_bounds__(256) void sum2bb(const ushort* __restrict__ a,
                                              const ushort* __restrict__ b,
                                              ushort* __restrict__ o, int nvec) {
  int i = blockIdx.x * 256 + threadIdx.x;
  if (i >= nvec) return;
  ushort8 va = *(const ushort8*)(a + (size_t)i * 8);
  ushort8 vb = *(const ushort8*)(b + (size_t)i * 8);
  ushort8 r;
#pragma unroll
  for (int e = 0; e < 8; ++e) r[e] = f2bf(bf2f(va[e]) + bf2f(vb[e]));
  *(ushort8*)(o + (size_t)i * 8) = r;
}

// f32 + f32 -> bf16 (8-wide)
__global__ __launch_bounds__(256) void sum2fb(const float* __restrict__ a,
                                              const float* __restrict__ b,
                                              ushort* __restrict__ o, int nvec) {
  int i = blockIdx.x * 256 + threadIdx.x;
  if (i >= nvec) return;
  const float4* pa = (const float4*)(a + (size_t)i * 8);
  const float4* pb = (const float4*)(b + (size_t)i * 8);
  float4 a0 = pa[0], a1 = pa[1], b0 = pb[0], b1 = pb[1];
  ushort8 r;
  r[0] = f2bf(a0.x + b0.x); r[1] = f2bf(a0.y + b0.y);
  r[2] = f2bf(a0.z + b0.z); r[3] = f2bf(a0.w + b0.w);
  r[4] = f2bf(a1.x + b1.x); r[5] = f2bf(a1.y + b1.y);
  r[6] = f2bf(a1.z + b1.z); r[7] = f2bf(a1.w + b1.w);
  *(ushort8*)(o + (size_t)i * 8) = r;
}

// ---------------------------------------------------------------------------
// gx GEMM: C[row'][col'] = sum_k A[src(row')][k] * W[col'][k], written in
// per-16x16-tile C-frag lane order: gx[dir][tid_m][tid_n][lane][rr] (ushort).
// row' is t-major: t = row'/NPAD, n = row'%NPAD + noff.
// ---------------------------------------------------------------------------
template <int MODE, bool NT>
__global__ __launch_bounds__(256) void gemm_gx(
    const ushort* __restrict__ A, const int* __restrict__ idx,
    const ushort* __restrict__ B, ushort* __restrict__ gx,
    int NPAD, int NSEQ, int T, int noff, int TMloc) {
  __shared__ __align__(16) ushort sa[128 * 32];
  const int tid = threadIdx.x;
  const int bm = blockIdx.x, bn = blockIdx.y;
  const int w = tid >> 6, l = tid & 63;
  const int wr = w >> 1, wc = w & 1;
  const int l15 = l & 15, lc = l >> 4;

  const int srow = tid >> 1;
  const int c0 = (tid & 1) * 2;
  int rloc = bm * 128 + srow;
  int t = rloc / NPAD;
  int nl = rloc - t * NPAD;
  int n = nl + noff;
  int grow;
  if (MODE == 0) grow = idx[n * T + t];
  else { int nn = n < NSEQ ? n : NSEQ - 1; grow = nn * T + t; }
  const ushort* srcrow = A + (size_t)grow * 256;

  const ushort* bbase[4];
#pragma unroll
  for (int i = 0; i < 4; ++i) {
    int ct = bn * 8 + wc * 4 + i;
    int dir = ct / 48;
    int ntAll = ct - dir * 48;
    bbase[i] = B + ((size_t)(dir * 48 + ntAll) * 8) * 512 + l * 8;
  }

  f32x4 acc[4][4];
#pragma unroll
  for (int mt = 0; mt < 4; ++mt)
#pragma unroll
    for (int nt = 0; nt < 4; ++nt) acc[mt][nt] = (f32x4){0.f, 0.f, 0.f, 0.f};

  ushort8 sta[2];
  bf16x8 bcur[4], bnxt[4];
#pragma unroll
  for (int j = 0; j < 2; ++j)
    sta[j] = *(const ushort8*)(srcrow + (c0 + j) * 8);
#pragma unroll
  for (int i = 0; i < 4; ++i) bcur[i] = *(const bf16x8*)(bbase[i]);

#pragma unroll
  for (int kk = 0; kk < 8; ++kk) {
    __syncthreads();
    *(ushort8*)(sa + srow * 32 + ((c0 + 0) ^ (srow & 3)) * 8) = sta[0];
    *(ushort8*)(sa + srow * 32 + ((c0 + 1) ^ (srow & 3)) * 8) = sta[1];
    __syncthreads();
    if (kk < 7) {
#pragma unroll
      for (int j = 0; j < 2; ++j)
        sta[j] = *(const ushort8*)(srcrow + (kk + 1) * 32 + (c0 + j) * 8);
#pragma unroll
      for (int i = 0; i < 4; ++i)
        bnxt[i] = *(const bf16x8*)(bbase[i] + (kk + 1) * 512);
    }
    bf16x8 af[4];
#pragma unroll
    for (int mt = 0; mt < 4; ++mt) {
      int row = wr * 64 + mt * 16 + l15;
      af[mt] = *(const bf16x8*)(sa + row * 32 + (lc ^ (row & 3)) * 8);
    }
#pragma unroll
    for (int mt = 0; mt < 4; ++mt)
#pragma unroll
      for (int nt = 0; nt < 4; ++nt)
        acc[mt][nt] = __builtin_amdgcn_mfma_f32_16x16x32_bf16(af[mt], bcur[nt],
                                                              acc[mt][nt], 0, 0, 0);
#pragma unroll
    for (int i = 0; i < 4; ++i) bcur[i] = bnxt[i];
  }

#pragma unroll
  for (int mt = 0; mt < 4; ++mt) {
    int tid_m = bm * 8 + wr * 4 + mt;
#pragma unroll
    for (int nt = 0; nt < 4; ++nt) {
      int ct = bn * 8 + wc * 4 + nt;
      int dir = ct / 48;
      int tid_n = ct - dir * 48;
      ushort4v o;
      o[0] = f2bf(acc[mt][nt][0]); o[1] = f2bf(acc[mt][nt][1]);
      o[2] = f2bf(acc[mt][nt][2]); o[3] = f2bf(acc[mt][nt][3]);
      ushort4v* dst = (ushort4v*)(gx + (((size_t)dir * TMloc + tid_m) * 48 + tid_n) * 256 + l * 4);
      if (NT) __builtin_nontemporal_store(o, dst);
      else *dst = o;
    }
  }
}

// ---------------------------------------------------------------------------
// Unified recurrent GRU kernel: 512 thr = 8 waves, 16 rows/block, one
// direction per block (dir = bid&1, rowgroup = bid>>1).  r,z Whh fragments
// cached in 128 VGPRs (loaded once); n-gate streamed from L2 each step.
// h double-buffered in LDS -> ONE raw s_barrier per step (only lgkmcnt
// drained; gx global loads stay in flight across it).
// ---------------------------------------------------------------------------
template <bool OUTF32>
__global__ __launch_bounds__(512) void gru_rec(
    const ushort* __restrict__ gx, const ushort* __restrict__ pWhh,
    const float* __restrict__ bih, const float* __restrict__ bhh,
    void* __restrict__ out_, int T, int NSEQ, int TPT, int TMloc, int noff) {
  __shared__ __align__(16) char shp[2][16 * 512];
  const int tid = threadIdx.x;
  const int w = tid >> 6, l = tid & 63;
  const int l15 = l & 15, lc = l >> 4;
  const int hi4 = lc << 2;
  const int dir = blockIdx.x & 1;
  const int rg = blockIdx.x >> 1;

  float bR[2], bZ[2], bNX[2], bNH[2];
#pragma unroll
  for (int q = 0; q < 2; ++q) {
    int jj = (2 * w + q) * 16 + l15;
    bR[q] = bih[dir * 768 + jj] + bhh[dir * 768 + jj];
    bZ[q] = bih[dir * 768 + 256 + jj] + bhh[dir * 768 + 256 + jj];
    bNX[q] = bih[dir * 768 + 512 + jj];
    bNH[q] = bhh[dir * 768 + 512 + jj];
  }
  const ushort* ph = pWhh + (size_t)dir * 196608;
  const size_t gxd = (size_t)dir * TMloc * 48 * 256;

  // cache r,z weight fragments (128 VGPR)
  bf16x8 wR[2][8], wZ[2][8];
#pragma unroll
  for (int q = 0; q < 2; ++q)
#pragma unroll
    for (int ks = 0; ks < 8; ++ks) {
      const ushort* pb = ph + (((2 * w + q) * 8 + ks) * 512) + l * 8;
      wR[q][ks] = *(const bf16x8*)(pb);
      wZ[q][ks] = *(const bf16x8*)(pb + 65536);
    }

  float hreg[2][4];
#pragma unroll
  for (int q = 0; q < 2; ++q)
#pragma unroll
    for (int r = 0; r < 4; ++r) hreg[q][r] = 0.f;

  for (int t = 0; t < T; ++t) {
    const int tt = dir ? (T - 1 - t) : t;
    const int tile = tt * TPT + rg;
    // gx loads issued early; consumed only at epilogue (stay in flight
    // across the barrier -- we drain lgkm only)
    ushort4v gq[2][3];
#pragma unroll
    for (int q = 0; q < 2; ++q)
#pragma unroll
      for (int g = 0; g < 3; ++g)
        gq[q][g] = __builtin_nontemporal_load(
            (const ushort4v*)(gx + gxd + ((size_t)tile * 48 + g * 16 + 2 * w + q) * 256 + l * 4));

    // write h(t-1) into buf[t&1] (regs -> LDS, incl. zeros at t=0)
    char* hb = shp[t & 1];
#pragma unroll
    for (int q = 0; q < 2; ++q)
#pragma unroll
      for (int r = 0; r < 4; ++r) {
        int i = hi4 + r;
        int jj = (2 * w + q) * 16 + l15;
        *(ushort*)(hb + i * 512 + ((jj * 2) ^ (i << 4))) = f2bf(hreg[q][r]);
      }
    asm volatile("s_waitcnt lgkmcnt(0)" ::: "memory");
    __builtin_amdgcn_s_barrier();
    __builtin_amdgcn_sched_barrier(0);

    f32x4 aR[2], aZ[2], aNH[2];
#pragma unroll
    for (int q = 0; q < 2; ++q) {
      aR[q] = (f32x4){bR[q], bR[q], bR[q], bR[q]};
      aZ[q] = (f32x4){bZ[q], bZ[q], bZ[q], bZ[q]};
      aNH[q] = (f32x4){bNH[q], bNH[q], bNH[q], bNH[q]};
    }
#pragma unroll
    for (int ks = 0; ks < 8; ++ks) {
      bf16x8 af = *(const bf16x8*)(hb + l15 * 512 + ((ks * 64 + lc * 16) ^ (l15 << 4)));
#pragma unroll
      for (int q = 0; q < 2; ++q) {
        bf16x8 bNw = *(const bf16x8*)(ph + 131072 + (((2 * w + q) * 8 + ks) * 512) + l * 8);
        aR[q] = __builtin_amdgcn_mfma_f32_16x16x32_bf16(af, wR[q][ks], aR[q], 0, 0, 0);
        aZ[q] = __builtin_amdgcn_mfma_f32_16x16x32_bf16(af, wZ[q][ks], aZ[q], 0, 0, 0);
        aNH[q] = __builtin_amdgcn_mfma_f32_16x16x32_bf16(af, bNw, aNH[q], 0, 0, 0);
      }
    }
#pragma unroll
    for (int q = 0; q < 2; ++q)
#pragma unroll
      for (int r = 0; r < 4; ++r) {
        float rr = sigm(aR[q][r] + bf2f(gq[q][0][r]));
        float zz = sigm(aZ[q][r] + bf2f(gq[q][1][r]));
        float nv = bf2f(gq[q][2][r]) + bNX[q] + rr * aNH[q][r];
        float e2 = __expf(-2.f * nv);
        float nn = (1.f - e2) / (1.f + e2);
        hreg[q][r] = (1.f - zz) * nn + zz * hreg[q][r];
      }
    // no second barrier: next step writes the OTHER LDS buffer
  }

#pragma unroll
  for (int q = 0; q < 2; ++q)
#pragma unroll
    for (int r = 0; r < 4; ++r) {
      int i = hi4 + r;
      int gn = noff + rg * 16 + i;
      if (gn < NSEQ) {
        int jj = (2 * w + q) * 16 + l15;
        size_t off = (size_t)dir * NSEQ * 256 + (size_t)gn * 256 + jj;
        if (OUTF32) ((float*)out_)[off] = hreg[q][r];
        else ((ushort*)out_)[off] = f2bf(hreg[q][r]);
      }
    }
}

// ---------------------------------------------------------------------------
// FC heads (validated R2/R3)
// ---------------------------------------------------------------------------
__global__ __launch_bounds__(128) void fc_head(
    const float* __restrict__ revf, const float* __restrict__ revb,
    const float* __restrict__ bizf, const float* __restrict__ bizb,
    const float* __restrict__ rW1, const float* __restrict__ rb1,
    const float* __restrict__ rW2, const float* __restrict__ rb2,
    const float* __restrict__ pW1, const float* __restrict__ pb1,
    const float* __restrict__ pW2, const float* __restrict__ pb2,
    float* __restrict__ out) {
  const int b = blockIdx.x;
  const int tid = threadIdx.x;
  const float *xf, *xb2, *W1, *b1, *W2, *b2;
  float* o;
  if (b < 128) {
    xf = revf + (size_t)b * 256; xb2 = revb + (size_t)b * 256;
    W1 = rW1; b1 = rb1; W2 = rW2; b2 = rb2; o = out + 8 + b;
  } else {
    int bb = b - 128;
    xf = bizf + (size_t)bb * 256; xb2 = bizb + (size_t)bb * 256;
    W1 = pW1; b1 = pb1; W2 = pW2; b2 = pb2; o = out + bb;
  }
  float acc = 0.f;
  const float4* f4 = (const float4*)xf;
  const float4* g4 = (const float4*)xb2;
  const float4* w4 = (const float4*)(W1 + (size_t)tid * 256);
#pragma unroll 4
  for (int k = 0; k < 64; ++k) {
    float4 a = f4[k], g = g4[k], w = w4[k];
    acc = fmaf(a.x + g.x, w.x, fmaf(a.y + g.y, w.y,
          fmaf(a.z + g.z, w.z, fmaf(a.w + g.w, w.w, acc))));
  }
  acc += b1[tid];
  const float LAM = 1.0507009873554805f, ALPHA = 1.6732632423543772f;
  float h = acc > 0.f ? LAM * acc : LAM * ALPHA * (__expf(acc) - 1.f);
  __shared__ float p[128];
  p[tid] = h * W2[tid];
  __syncthreads();
  if (tid == 0) {
    float s = b2[0];
#pragma unroll 8
    for (int i = 0; i < 128; ++i) s += p[i];
    *o = s;
  }
}

extern "C" void kernel_launch(void* const* d_in, const int* in_sizes, int n_in,
                              void* d_out, int out_size, void* d_ws, size_t ws_size,
                              hipStream_t stream) {
  const int*   inputs = (const int*)d_in[0];
  const float* emb    = (const float*)d_in[1];
  const float* w_Wih  = (const float*)d_in[2];
  const float* w_Whh  = (const float*)d_in[3];
  const float* w_bih  = (const float*)d_in[4];
  const float* w_bhh  = (const float*)d_in[5];
  const float* s_Wih  = (const float*)d_in[6];
  const float* s_Whh  = (const float*)d_in[7];
  const float* s_bih  = (const float*)d_in[8];
  const float* s_bhh  = (const float*)d_in[9];
  const float* r_Wih  = (const float*)d_in[10];
  const float* r_Whh  = (const float*)d_in[11];
  const float* r_bih  = (const float*)d_in[12];
  const float* r_bhh  = (const float*)d_in[13];
  const float* rfc_W1 = (const float*)d_in[14];
  const float* rfc_b1 = (const float*)d_in[15];
  const float* rfc_W2 = (const float*)d_in[16];
  const float* rfc_b2 = (const float*)d_in[17];
  const float* pfc_W1 = (const float*)d_in[18];
  const float* pfc_b1 = (const float*)d_in[19];
  const float* pfc_W2 = (const float*)d_in[20];
  const float* pfc_b2 = (const float*)d_in[21];
  float* out = (float*)d_out;

  char* ws = (char*)d_ws;
  ushort* pmf    = (ushort*)(ws);                    //  4,718,592
  ushort* embb   = (ushort*)(ws + 4718592);          // 15,360,000
  ushort* sentA  = (ushort*)(ws + 20078592);         //  1,048,576
  ushort* sent_f = (ushort*)(ws + 21127168);         //  2,097,152 (both dirs)
  float*  rev_f  = (float*)(ws + 23224320);          //    262,144 (both dirs)
  ushort* revsum = (ushort*)(ws + 23486464);         //     65,536
  float*  biz_f  = (float*)(ws + 23552000);          //     16,384
  ushort* gxs    = (ushort*)(ws + 23568384);         //  6,291,456
  ushort* gxr    = (ushort*)(ws + 29859840);         //    786,432
  ushort* gxw    = (ushort*)(ws + 30646272);         // up to 201,326,592
  float* rev_b = rev_f + 32768;
  float* biz_b = biz_f + 2048;
  ushort* sent_b = sent_f + 524288;

  const size_t gx_full = 201326592ull;
  const size_t fixed_end = 30646272ull;
  int NP = 32;
  for (int cand = 1; cand <= 32; cand <<= 1) {
    if (ws_size >= fixed_end + gx_full / cand) { NP = cand; break; }
  }
  const int slice = 2048 / NP;
  const int TMp = 4096 / NP;

  embcvt<<<3750, 256, 0, stream>>>(emb, embb);
  pack_mfma<<<1152, 256, 0, stream>>>(w_Wih, w_Whh, s_Wih, s_Whh, r_Wih, r_Whh, pmf);

  // word level (per pass: gx GEMM then recurrent; 256 blocks/pass at NP=1)
  for (int p = 0; p < NP; ++p) {
    gemm_gx<0, true><<<dim3(512 / NP, 12), 256, 0, stream>>>(
        embb, inputs, pmf, gxw, slice, 2048, 32, p * slice, TMp);
    gru_rec<false><<<(slice / 16) * 2, 512, 0, stream>>>(
        gxw, pmf + 393216, w_bih, w_bhh, sent_f, 32, 2048, slice / 16, TMp, p * slice);
  }
  sum2bb<<<256, 256, 0, stream>>>(sent_f, sent_b, sentA, 65536);

  // sentence level
  gemm_gx<1, false><<<dim3(16, 12), 256, 0, stream>>>(
      sentA, nullptr, pmf + 2 * 393216, gxs, 128, 128, 16, 0, 128);
  gru_rec<true><<<16, 512, 0, stream>>>(gxs, pmf + 3 * 393216, s_bih, s_bhh,
                                        rev_f, 16, 128, 8, 128, 0);
  sum2fb<<<16, 256, 0, stream>>>(rev_f, rev_b, revsum, 4096);

  // review level (rows padded 8->16)
  gemm_gx<1, false><<<dim3(2, 12), 256, 0, stream>>>(
      revsum, nullptr, pmf + 4 * 393216, gxr, 16, 8, 16, 0, 16);
  gru_rec<true><<<2, 512, 0, stream>>>(gxr, pmf + 5 * 393216, r_bih, r_bhh,
                                       biz_f, 16, 8, 1, 16, 0);

  fc_head<<<136, 128, 0, stream>>>(rev_f, rev_b, biz_f, biz_b,
                                   rfc_W1, rfc_b1, rfc_W2, rfc_b2,
                                   pfc_W1, pfc_b1, pfc_W2, pfc_b2, out);
}